// Round 3
// baseline (276.845 us; speedup 1.0000x reference)
//
#include <hip/hip_runtime.h>
#include <hip/hip_bf16.h>

typedef __bf16 bf16x8 __attribute__((ext_vector_type(8)));
typedef float f32x16 __attribute__((ext_vector_type(16)));

#define NQ     10
#define M_ROWS 16384
#define N_COLS 1024
#define K_DIM  4096

// ---------------------------------------------------------------- helpers
__device__ __forceinline__ void gload_lds16(const __hip_bfloat16* g, __hip_bfloat16* l) {
  __builtin_amdgcn_global_load_lds(
      (const __attribute__((address_space(1))) void*)g,
      (__attribute__((address_space(3))) void*)l,
      16, 0, 0);
}

// ---------------------------------------------------------------- prep
// W1 (4096 x 10) -> W1T (10 x 4096) fp32
__global__ void __launch_bounds__(256) tr_w1(const float* __restrict__ W1,
                                             float* __restrict__ W1T) {
  int f = blockIdx.x * 256 + threadIdx.x;
#pragma unroll
  for (int j = 0; j < NQ; j++)
    W1T[j * K_DIM + f] = W1[f * NQ + j];
}

// W2 (1024 x 4096) fp32 -> bf16
__global__ void __launch_bounds__(256) cvt_w2(const float* __restrict__ in,
                                              __hip_bfloat16* __restrict__ out) {
  int i = (blockIdx.x * 256 + threadIdx.x) * 4;
  float4 v = *(const float4*)(in + i);
  union { __hip_bfloat16 h[4]; uint2 u; } p;
  p.h[0] = __float2bfloat16(v.x);
  p.h[1] = __float2bfloat16(v.y);
  p.h[2] = __float2bfloat16(v.z);
  p.h[3] = __float2bfloat16(v.w);
  *(uint2*)(out + i) = p.u;
}

// ---------------------------------------------------------------- h = relu(q_out @ W1^T) bf16
// closed form: q[0] = prod_{j=1..9} cos; q[k] = prod_{j=0..k} cos
// coalesced W1T reads (lanes stride 32B) + uint4 stores (lanes stride 16B)
__global__ void __launch_bounds__(256) compute_h(const float* __restrict__ x,
                                                 const float* __restrict__ qp,
                                                 const float* __restrict__ W1T,
                                                 __hip_bfloat16* __restrict__ h) {
  __shared__ float qs[8][NQ];
  const int tid = threadIdx.x;
  const int r0 = blockIdx.x * 8;

  if (tid < 8 * NQ) {
    int r = tid / NQ, j = tid % NQ;
    qs[r][j] = cosf(x[(r0 + r) * NQ + j] + qp[j]);
  }
  __syncthreads();
  if (tid < 8) {
    float c[NQ];
#pragma unroll
    for (int j = 0; j < NQ; j++) c[j] = qs[tid][j];
    float pref = c[0];
    float prod19 = 1.f;
#pragma unroll
    for (int j = 1; j < NQ; j++) prod19 *= c[j];
    qs[tid][0] = prod19;
#pragma unroll
    for (int k = 1; k < NQ; k++) { pref *= c[k]; qs[tid][k] = pref; }
  }
  __syncthreads();

#pragma unroll 1
  for (int k = 0; k < 2; k++) {
    const int col0 = k * 2048 + tid * 8;
    float w[8][NQ];
#pragma unroll
    for (int j = 0; j < NQ; j++) {
      float4 a = *(const float4*)(W1T + j * K_DIM + col0);
      float4 b = *(const float4*)(W1T + j * K_DIM + col0 + 4);
      w[0][j] = a.x; w[1][j] = a.y; w[2][j] = a.z; w[3][j] = a.w;
      w[4][j] = b.x; w[5][j] = b.y; w[6][j] = b.z; w[7][j] = b.w;
    }
#pragma unroll
    for (int r = 0; r < 8; r++) {
      float q[NQ];
#pragma unroll
      for (int j = 0; j < NQ; j++) q[j] = qs[r][j];
      union { __hip_bfloat16 hh[8]; uint4 u; } pk;
#pragma unroll
      for (int c = 0; c < 8; c++) {
        float acc = 0.f;
#pragma unroll
        for (int j = 0; j < NQ; j++) acc = fmaf(q[j], w[c][j], acc);
        pk.hh[c] = __float2bfloat16(fmaxf(acc, 0.f));
      }
      *(uint4*)(h + (r0 + r) * K_DIM + col0) = pk.u;
    }
  }
}

// ---------------------------------------------------------------- C = A(MxK) * B(NxK)^T, bf16 in fp32 out
// 32x32x16 MFMA (4096 FLOP/cyc vs 3413 for 16x16x32, half the issue count),
// XOR bank swizzle, XCD-aware decode, global_load_lds x16 staging.
__global__ void __launch_bounds__(256) gemm_bt(const __hip_bfloat16* __restrict__ A,
                                               const __hip_bfloat16* __restrict__ B,
                                               float* __restrict__ C) {
  __shared__ __align__(16) __hip_bfloat16 As[128 * 64];
  __shared__ __align__(16) __hip_bfloat16 Bs[128 * 64];

  const int tid  = threadIdx.x;
  const int wave = tid >> 6;
  const int lane = tid & 63;
  const int l31  = lane & 31;
  const int l5   = lane >> 5;   // half-wave
  const int l7   = lane & 7;
  const int wm   = (wave & 1) * 64;
  const int wn   = (wave >> 1) * 64;

  // XCD-aware decode: XCD d owns row-tiles [16d,16d+16) x all 8 col-tiles
  const int L    = blockIdx.x;
  const int xcd  = L & 7;
  const int idx  = L >> 3;
  const int col0 = (idx & 7) * 128;
  const int row0 = ((xcd << 4) | (idx >> 3)) * 128;

  const int ldr = wave * 8 + (lane >> 3);
  const int ldc = ((l7 ^ (lane >> 3)) << 3);   // LDS[R][p] = global[R][p^(R&7)]

  f32x16 acc[2][2];
#pragma unroll
  for (int i = 0; i < 2; i++)
#pragma unroll
    for (int j = 0; j < 2; j++)
#pragma unroll
      for (int r = 0; r < 16; r++) acc[i][j][r] = 0.f;

  for (int k0 = 0; k0 < K_DIM; k0 += 64) {
#pragma unroll
    for (int i = 0; i < 4; i++) {
      int r = i * 32 + ldr;
      gload_lds16(A + (row0 + r) * K_DIM + k0 + ldc, As + (i * 32 + wave * 8) * 64);
      gload_lds16(B + (col0 + r) * K_DIM + k0 + ldc, Bs + (i * 32 + wave * 8) * 64);
    }
    __syncthreads();

#pragma unroll
    for (int kk = 0; kk < 64; kk += 16) {
      // A-frag: row=lane&31, k=(lane>>5)*8+j ; swizzled chunk = ((kk>>3)+l5)^l7
      const int ch = ((((kk >> 3) + l5) ^ l7) << 3);
      bf16x8 af[2], bb[2];
#pragma unroll
      for (int f = 0; f < 2; f++)
        af[f] = *(const bf16x8*)(As + (wm + f * 32 + l31) * 64 + ch);
#pragma unroll
      for (int f = 0; f < 2; f++)
        bb[f] = *(const bf16x8*)(Bs + (wn + f * 32 + l31) * 64 + ch);
#pragma unroll
      for (int fm = 0; fm < 2; fm++)
#pragma unroll
        for (int fn = 0; fn < 2; fn++)
          acc[fm][fn] = __builtin_amdgcn_mfma_f32_32x32x16_bf16(af[fm], bb[fn], acc[fm][fn], 0, 0, 0);
    }
    __syncthreads();
  }

  // epilogue: C/D layout col=lane&31, row=(reg&3)+8*(reg>>2)+4*(lane>>5)
#pragma unroll
  for (int fm = 0; fm < 2; fm++) {
#pragma unroll
    for (int fn = 0; fn < 2; fn++) {
      const int colb = col0 + wn + fn * 32 + l31;
      const int rowb = row0 + wm + fm * 32 + 4 * l5;
#pragma unroll
      for (int reg = 0; reg < 16; reg++) {
        int row = rowb + (reg & 3) + 8 * (reg >> 2);
        C[row * N_COLS + colb] = acc[fm][fn][reg];
      }
    }
  }
}

// ---------------------------------------------------------------- launch
extern "C" void kernel_launch(void* const* d_in, const int* in_sizes, int n_in,
                              void* d_out, int out_size, void* d_ws, size_t ws_size,
                              hipStream_t stream) {
  const float* x  = (const float*)d_in[0];   // 32*512*10
  const float* qp = (const float*)d_in[1];   // 10
  const float* W1 = (const float*)d_in[2];   // 4096*10
  const float* W2 = (const float*)d_in[3];   // 1024*4096
  float* out = (float*)d_out;                // 32*512*1024 fp32

  char* ws = (char*)d_ws;
  float*          W1T = (float*)ws;                                  // 163840 B
  __hip_bfloat16* W2b = (__hip_bfloat16*)(ws + 163840);              // 8388608 B
  __hip_bfloat16* hbf = (__hip_bfloat16*)(ws + 163840 + 8388608);    // 134217728 B

  tr_w1<<<16, 256, 0, stream>>>(W1, W1T);
  cvt_w2<<<4096, 256, 0, stream>>>(W2, W2b);
  compute_h<<<M_ROWS / 8, 256, 0, stream>>>(x, qp, W1T, hbf);
  gemm_bt<<<(N_COLS / 128) * (M_ROWS / 128), 256, 0, stream>>>(hbf, W2b, out);
}